// Round 8
// baseline (289.025 us; speedup 1.0000x reference)
//
#include <hip/hip_runtime.h>
#include <hip/hip_bf16.h>
#include <cstdint>

// GateAttention, restructured:
//   xcW|G1 = xc @ [WC | V_top]   (relu on xcW half; G1 bf16 -> ws)
//   xqW|xqV = xq @ [WQ | V_bot]  (relu on xqW half)
//   attn: S = xcW.xqW^T, softmax+mask, O = P @ xqV, out = sigmoid(G1 + O)
// Round 8: attn drops ALL QK LDS staging (inputs are L2-resident; m169
// lesson): barrier-free QK with register double-buffered global fragment
// loads, 64-row/4-wave blocks, grid 512 = 2 blocks/CU. LDS only for P +
// softmax reduce. gemm4b unchanged (107us proven).
// B=16, LC=2048, LQ=256, D=768, F=768.

using bf16 = __hip_bfloat16;
typedef __attribute__((ext_vector_type(8))) __bf16 bf16x8;
typedef __attribute__((ext_vector_type(4))) float f32x4;

typedef __attribute__((address_space(1))) const uint32_t GU32;
typedef __attribute__((address_space(3))) uint32_t LU32;

__device__ __forceinline__ void gll16(const bf16* g, bf16* l) {
  __builtin_amdgcn_global_load_lds((GU32*)g, (LU32*)l, 16, 0, 0);
}
__device__ __forceinline__ f32x4 mfma_bf16(bf16x8 a, bf16x8 b, f32x4 c) {
  return __builtin_amdgcn_mfma_f32_16x16x32_bf16(a, b, c, 0, 0, 0);
}
__device__ __forceinline__ bf16x8 ld_frag(const bf16* p) {
  return *reinterpret_cast<const bf16x8*>(p);
}
// LDS chunk swizzle (4 chunks of 16B per 64B row)
__device__ __forceinline__ int swz(int r) { return (r & 3) ^ ((r >> 2) & 1); }

__device__ __forceinline__ unsigned short f2bf_bits(float x) {
  bf16 b = __float2bfloat16(x);
  union { bf16 b; unsigned short s; } u;
  u.b = b;
  return u.s;
}

// ---------- 4x fused transpose f32 [768][768] -> bf16 [768][768]^T ----------
__global__ void transpose4(const float* __restrict__ s0, const float* __restrict__ s1,
                           const float* __restrict__ s2, const float* __restrict__ s3,
                           bf16* __restrict__ d0, bf16* __restrict__ d1,
                           bf16* __restrict__ d2, bf16* __restrict__ d3) {
  __shared__ float tile[32][33];
  const int z = blockIdx.z;
  const float* in = (z == 0) ? s0 : (z == 1) ? s1 : (z == 2) ? s2 : s3;
  bf16* out = (z == 0) ? d0 : (z == 1) ? d1 : (z == 2) ? d2 : d3;
  int c0 = blockIdx.x * 32, r0 = blockIdx.y * 32;
  int tx = threadIdx.x, ty = threadIdx.y;
#pragma unroll
  for (int i = ty; i < 32; i += 8)
    tile[i][tx] = in[(long)(r0 + i) * 768 + (c0 + tx)];
  __syncthreads();
#pragma unroll
  for (int i = ty; i < 32; i += 8)
    out[(long)(c0 + i) * 768 + (r0 + tx)] = __float2bfloat16(tile[tx][i]);
}

// ---------- transpose bf16 [R][C] -> bf16 [C][R], batched ----------
__global__ void transpose_bf16(const bf16* __restrict__ in, bf16* __restrict__ out,
                               int R, int C, long ibs, long obs) {
  __shared__ bf16 tile[32][33];
  const bf16* inb = in + (long)blockIdx.z * ibs;
  bf16* outb = out + (long)blockIdx.z * obs;
  int c0 = blockIdx.x * 32, r0 = blockIdx.y * 32;
  int tx = threadIdx.x, ty = threadIdx.y;
#pragma unroll
  for (int i = ty; i < 32; i += 8)
    tile[i][tx] = inb[(long)(r0 + i) * C + (c0 + tx)];
  __syncthreads();
#pragma unroll
  for (int i = ty; i < 32; i += 8)
    outb[(long)(c0 + i) * R + (r0 + tx)] = tile[tx][i];
}

// ---------- flat f32 -> bf16 convert, grid-stride ----------
__global__ void convert_flat(const float* __restrict__ in, bf16* __restrict__ out, long n4) {
  long stride = (long)gridDim.x * blockDim.x;
  for (long i = (long)blockIdx.x * blockDim.x + threadIdx.x; i < n4; i += stride) {
    float4 v = reinterpret_cast<const float4*>(in)[i];
    ushort4 o;
    o.x = f2bf_bits(v.x);
    o.y = f2bf_bits(v.y);
    o.z = f2bf_bits(v.z);
    o.w = f2bf_bits(v.w);
    reinterpret_cast<ushort4*>(out)[i] = o;
  }
}

// ---------- 128x128 GEMM with split epilogue (small xq projection) ----------
__global__ __launch_bounds__(256) void gemm_bt_split(
    const bf16* __restrict__ A, long lda,
    const bf16* __restrict__ Bt, long ldb,
    bf16* __restrict__ O1, bf16* __restrict__ O2, int K) {
  __shared__ __align__(16) bf16 As[128 * 32];
  __shared__ __align__(16) bf16 Bs[128 * 32];
  const int tid = threadIdx.x;
  const int wave = tid >> 6;
  const int lane = tid & 63;
  const int l16 = lane & 15;
  const int kh = lane >> 4;
  const int wm = (wave >> 1) * 64;
  const int wn = (wave & 1) * 64;
  const long row0 = (long)blockIdx.x * 128;
  const long col0 = (long)blockIdx.y * 128;
  const int srow = tid >> 2;
  const int scol = ((tid & 3) ^ swz(srow)) * 8;

  const bf16* ap0 = A + (row0 + srow) * lda + scol;
  const bf16* ap1 = ap0 + 64 * lda;
  const bf16* bp0 = Bt + (col0 + srow) * ldb + scol;
  const bf16* bp1 = bp0 + 64 * ldb;
  bf16* as0 = As + wave * 512;
  bf16* as1 = as0 + 2048;
  bf16* bs0 = Bs + wave * 512;
  bf16* bs1 = bs0 + 2048;

  const int xc = (kh ^ swz(l16)) * 8;
  f32x4 acc[4][4] = {};

  for (int k0 = 0; k0 < K; k0 += 32) {
    gll16(ap0 + k0, as0);
    gll16(ap1 + k0, as1);
    gll16(bp0 + k0, bs0);
    gll16(bp1 + k0, bs1);
    __syncthreads();
    bf16x8 af[4], bfr[4];
#pragma unroll
    for (int i = 0; i < 4; ++i)
      af[i] = ld_frag(As + (wm + i * 16 + l16) * 32 + xc);
#pragma unroll
    for (int j = 0; j < 4; ++j)
      bfr[j] = ld_frag(Bs + (wn + j * 16 + l16) * 32 + xc);
#pragma unroll
    for (int i = 0; i < 4; ++i)
#pragma unroll
      for (int j = 0; j < 4; ++j)
        acc[i][j] = mfma_bf16(af[i], bfr[j], acc[i][j]);
    __syncthreads();
  }

  const bool isO1 = col0 < 768;
#pragma unroll
  for (int i = 0; i < 4; ++i)
#pragma unroll
    for (int j = 0; j < 4; ++j)
#pragma unroll
      for (int r = 0; r < 4; ++r) {
        long row = row0 + wm + i * 16 + kh * 4 + r;
        long col = col0 + wn + j * 16 + l16;
        float v = acc[i][j][r];
        if (isO1)
          O1[row * 768 + col] = __float2bfloat16(fmaxf(v, 0.0f));
        else
          O2[row * 768 + (col - 768)] = __float2bfloat16(v);
      }
}

// ---------- 256x256 GEMM, BK=32, 4-buffer LDS, 3-tile prefetch depth -------
// cols [0,768): relu -> O1 bf16 (xcW) ; cols [768,1536): plain -> O2 bf16 (G1).
__global__ __launch_bounds__(512, 2) void gemm4b(
    const bf16* __restrict__ A, long lda,
    const bf16* __restrict__ Bt, long ldb,
    bf16* __restrict__ O1, bf16* __restrict__ O2, int K) {
  extern __shared__ __align__(16) bf16 smem[];  // 4 bufs x (A 8192 + B 8192) bf16
  const int tid = threadIdx.x;
  const int wid = tid >> 6;
  const int lane = tid & 63;
  const int l15 = lane & 15;
  const int g = lane >> 4;
  const int wm = wid >> 2;
  const int wn = wid & 3;

  const int lin = blockIdx.x;          // 0..767
  const int per = (int)gridDim.x >> 3; // 96
  const int wgid = (lin & 7) * per + (lin >> 3);
  const long row0 = (long)(wgid / 6) * 256;
  const long col0 = (long)(wgid % 6) * 256;

  const int srow = lane >> 2;
  const int sc = ((lane & 3) ^ swz(srow)) * 8;
  const int w16 = wid * 16;
  const bf16* Ab = A + (row0 + srow) * lda + sc;
  const bf16* Bb = Bt + (col0 + srow) * ldb + sc;

  f32x4 acc[8][4] = {};

  auto stageA = [&](int buf, int kk) {
    bf16* d = smem + buf * 16384 + w16 * 32;
    gll16(Ab + (long)w16 * lda + kk, d);
    gll16(Ab + (long)(128 + w16) * lda + kk, d + 128 * 32);
  };
  auto stageB = [&](int buf, int kk) {
    bf16* d = smem + buf * 16384 + 8192 + w16 * 32;
    gll16(Bb + (long)w16 * ldb + kk, d);
    gll16(Bb + (long)(128 + w16) * ldb + kk, d + 128 * 32);
  };
  const int xc = (g ^ swz(l15)) * 8;
  auto ldA = [&](int buf, int m) {
    int row = wm * 128 + m * 16 + l15;
    return ld_frag(smem + buf * 16384 + row * 32 + xc);
  };
  auto ldB = [&](int buf, int n) {
    int row = wn * 64 + n * 16 + l15;
    return ld_frag(smem + buf * 16384 + 8192 + row * 32 + xc);
  };

  stageA(0, 0);
  stageB(0, 0);
  stageA(1, 32);
  stageB(1, 32);
  stageA(2, 64);
  stageB(2, 64);
  asm volatile("s_waitcnt vmcnt(8)\n\ts_barrier" ::: "memory");

  const int NT = K >> 5;  // 24
  bf16x8 av[4], bv[4];

  for (int t = 0; t < NT; ++t) {
    const int cur = t & 3;
    const int pfb = (t + 3) & 3;
    const bool pf = (t + 3) < NT;
    const int kk = (t + 3) << 5;

#pragma unroll
    for (int n = 0; n < 4; ++n) bv[n] = ldB(cur, n);
#pragma unroll
    for (int m = 0; m < 4; ++m) av[m] = ldA(cur, m);
    if (pf) stageA(pfb, kk);
    __builtin_amdgcn_s_barrier();
    __builtin_amdgcn_s_setprio(1);
#pragma unroll
    for (int m = 0; m < 4; ++m)
#pragma unroll
      for (int n = 0; n < 4; ++n) acc[m][n] = mfma_bf16(av[m], bv[n], acc[m][n]);
    __builtin_amdgcn_s_setprio(0);
    __builtin_amdgcn_s_barrier();

#pragma unroll
    for (int m = 0; m < 4; ++m) av[m] = ldA(cur, 4 + m);
    if (pf) stageB(pfb, kk);
    __builtin_amdgcn_s_barrier();
    __builtin_amdgcn_s_setprio(1);
#pragma unroll
    for (int m = 0; m < 4; ++m)
#pragma unroll
      for (int n = 0; n < 4; ++n)
        acc[4 + m][n] = mfma_bf16(av[m], bv[n], acc[4 + m][n]);
    __builtin_amdgcn_s_setprio(0);

    if (t <= NT - 4)
      asm volatile("s_waitcnt vmcnt(8)\n\ts_barrier" ::: "memory");
    else if (t == NT - 3)
      asm volatile("s_waitcnt vmcnt(4)\n\ts_barrier" ::: "memory");
    else if (t == NT - 2)
      asm volatile("s_waitcnt vmcnt(0)\n\ts_barrier" ::: "memory");
  }

  const bool isO1 = col0 < 768;
#pragma unroll
  for (int m = 0; m < 8; ++m)
#pragma unroll
    for (int n = 0; n < 4; ++n)
#pragma unroll
      for (int r = 0; r < 4; ++r) {
        long row = row0 + wm * 128 + m * 16 + g * 4 + r;
        long col = col0 + wn * 64 + n * 16 + l15;
        float v = acc[m][n][r];
        if (isO1)
          O1[row * 768 + col] = __float2bfloat16(fmaxf(v, 0.0f));
        else
          O2[row * 768 + (col - 768)] = __float2bfloat16(v);
      }
}

// ---------- fused attention + gate: 64 c-rows, 4 waves, NO QK staging ------
// QK reads A/B fragments directly from global (L2-resident), register
// double-buffered, barrier-free. LDS only: P[64][264] + wred/wsum = 69632 B
// -> 2 blocks/CU (grid 512).
__global__ __launch_bounds__(256) void attn4(
    const bf16* __restrict__ xcW, const bf16* __restrict__ xqW,
    const bf16* __restrict__ xqVT, const bf16* __restrict__ G1,
    const int* __restrict__ qlen_arr, float* __restrict__ out) {
  extern __shared__ __align__(16) bf16 smem[];
  bf16* P = smem;                         // [64][264]
  float* wred = (float*)(smem + 33792);   // [64][4]
  float* wsum = wred + 256;               // [64][4]

  // XCD-chunked, batch-grouped: XCD x serves batches 2x,2x+1.
  const int lin = blockIdx.x;     // 0..511
  const int xcd = lin & 7;
  const int jj = lin >> 3;        // 0..63
  const int b = xcd * 2 + (jj >> 5);
  const int ct = jj & 31;

  const int tid = threadIdx.x;
  const int wc = tid >> 6;        // 0..3
  const int lane = tid & 63;
  const int l16 = lane & 15;
  const int kh = lane >> 4;

  const long crow0 = (long)b * 2048 + (long)ct * 64;
  const bf16* Ap = xcW + (crow0 + l16) * 768 + kh * 8;
  const bf16* Bp = xqW + ((long)b * 256 + wc * 64 + l16) * 768 + kh * 8;

  // ---- QK: barrier-free, reg double-buffered global fragment stream ----
  bf16x8 a0[4], b0[4], a1[4], b1[4];
#pragma unroll
  for (int i = 0; i < 4; ++i) a0[i] = ld_frag(Ap + i * 16 * 768);
#pragma unroll
  for (int j = 0; j < 4; ++j) b0[j] = ld_frag(Bp + j * 16 * 768);

  f32x4 acc[4][4] = {};
  for (int t = 0; t < 24; t += 2) {
    if (t + 1 < 24) {
      const bf16* ap = Ap + (t + 1) * 32;
      const bf16* bp = Bp + (t + 1) * 32;
#pragma unroll
      for (int i = 0; i < 4; ++i) a1[i] = ld_frag(ap + i * 16 * 768);
#pragma unroll
      for (int j = 0; j < 4; ++j) b1[j] = ld_frag(bp + j * 16 * 768);
    }
    __builtin_amdgcn_s_setprio(1);
#pragma unroll
    for (int i = 0; i < 4; ++i)
#pragma unroll
      for (int j = 0; j < 4; ++j)
        acc[i][j] = mfma_bf16(a0[i], b0[j], acc[i][j]);
    __builtin_amdgcn_s_setprio(0);
    if (t + 2 < 24) {
      const bf16* ap = Ap + (t + 2) * 32;
      const bf16* bp = Bp + (t + 2) * 32;
#pragma unroll
      for (int i = 0; i < 4; ++i) a0[i] = ld_frag(ap + i * 16 * 768);
#pragma unroll
      for (int j = 0; j < 4; ++j) b0[j] = ld_frag(bp + j * 16 * 768);
    }
    __builtin_amdgcn_s_setprio(1);
#pragma unroll
    for (int i = 0; i < 4; ++i)
#pragma unroll
      for (int j = 0; j < 4; ++j)
        acc[i][j] = mfma_bf16(a1[i], b1[j], acc[i][j]);
    __builtin_amdgcn_s_setprio(0);
  }

  const float scale = 0.036084391824351615f;  // 1/sqrt(768)
  const int qlen = qlen_arr[b];

#pragma unroll
  for (int i = 0; i < 4; ++i)
#pragma unroll
    for (int j = 0; j < 4; ++j) {
      int col = wc * 64 + j * 16 + l16;
      float m = (col >= qlen) ? -1.0e12f : 0.0f;
#pragma unroll
      for (int r = 0; r < 4; ++r)
        acc[i][j][r] = acc[i][j][r] * scale + m;
    }

#pragma unroll
  for (int i = 0; i < 4; ++i)
#pragma unroll
    for (int r = 0; r < 4; ++r) {
      float mx = fmaxf(fmaxf(acc[i][0][r], acc[i][1][r]),
                       fmaxf(acc[i][2][r], acc[i][3][r]));
      mx = fmaxf(mx, __shfl_xor(mx, 1));
      mx = fmaxf(mx, __shfl_xor(mx, 2));
      mx = fmaxf(mx, __shfl_xor(mx, 4));
      mx = fmaxf(mx, __shfl_xor(mx, 8));
      if (l16 == 0) wred[(i * 16 + kh * 4 + r) * 4 + wc] = mx;
    }
  __syncthreads();

#pragma unroll
  for (int i = 0; i < 4; ++i)
#pragma unroll
    for (int r = 0; r < 4; ++r) {
      int row = i * 16 + kh * 4 + r;
      float gm = fmaxf(fmaxf(wred[row * 4 + 0], wred[row * 4 + 1]),
                       fmaxf(wred[row * 4 + 2], wred[row * 4 + 3]));
      float s = 0.0f;
#pragma unroll
      for (int j = 0; j < 4; ++j) {
        float e = expf(acc[i][j][r] - gm);
        acc[i][j][r] = e;
        s += e;
      }
      s += __shfl_xor(s, 1);
      s += __shfl_xor(s, 2);
      s += __shfl_xor(s, 4);
      s += __shfl_xor(s, 8);
      if (l16 == 0) wsum[row * 4 + wc] = s;
    }
  __syncthreads();

#pragma unroll
  for (int i = 0; i < 4; ++i)
#pragma unroll
    for (int r = 0; r < 4; ++r) {
      int row = i * 16 + kh * 4 + r;
      float inv = 1.0f / (wsum[row * 4 + 0] + wsum[row * 4 + 1] +
                          wsum[row * 4 + 2] + wsum[row * 4 + 3]);
#pragma unroll
      for (int j = 0; j < 4; ++j)
        P[row * 264 + wc * 64 + j * 16 + l16] = __float2bfloat16(acc[i][j][r] * inv);
    }
  __syncthreads();

  // hoist P fragments (reused across all 3 nb sweeps)
  bf16x8 pf[4][8];
#pragma unroll
  for (int i = 0; i < 4; ++i)
#pragma unroll
    for (int kk = 0; kk < 8; ++kk)
      pf[i][kk] = ld_frag(P + (i * 16 + l16) * 264 + kk * 32 + kh * 8);

  for (int nb = 0; nb < 3; ++nb) {
    const int n0 = nb * 256 + wc * 64;
    const bf16* btp = xqVT + ((long)b * 768 + n0) * 256;
    f32x4 a2[4][4] = {};
#pragma unroll
    for (int kk = 0; kk < 8; ++kk) {
      bf16x8 vf[4];
#pragma unroll
      for (int j = 0; j < 4; ++j)
        vf[j] = ld_frag(btp + (j * 16 + l16) * 256 + kk * 32 + kh * 8);
#pragma unroll
      for (int i = 0; i < 4; ++i)
#pragma unroll
        for (int j = 0; j < 4; ++j)
          a2[i][j] = mfma_bf16(pf[i][kk], vf[j], a2[i][j]);
    }
#pragma unroll
    for (int i = 0; i < 4; ++i)
#pragma unroll
      for (int j = 0; j < 4; ++j)
#pragma unroll
        for (int r = 0; r < 4; ++r) {
          long row = crow0 + i * 16 + kh * 4 + r;
          int col = n0 + j * 16 + l16;
          float v = a2[i][j][r] + __bfloat162float(G1[row * 768 + col]);
          out[row * 768 + col] = 1.0f / (1.0f + __expf(-v));
        }
  }
}

extern "C" void kernel_launch(void* const* d_in, const int* in_sizes, int n_in,
                              void* d_out, int out_size, void* d_ws, size_t ws_size,
                              hipStream_t stream) {
  const float* x_cont = (const float*)d_in[0];  // [16,2048,768]
  const float* x_ques = (const float*)d_in[1];  // [16,256,768]
  const int* ques_len = (const int*)d_in[2];    // [16]
  const float* WC = (const float*)d_in[3];      // [768,768]
  const float* WQ = (const float*)d_in[4];      // [768,768]
  const float* V = (const float*)d_in[5];       // [1536,768]
  float* out = (float*)d_out;                   // [32768,768] f32

  // ws layout (bf16 elements)
  bf16* Wct = (bf16*)d_ws;                       // [1536][768] = [WC^T ; Vtop^T]
  bf16* Wqt = Wct + (long)1536 * 768;            // [1536][768] = [WQ^T ; Vbot^T]
  bf16* xcB = Wqt + (long)1536 * 768;            // [32768][768]
  bf16* xqB = xcB + (long)32768 * 768;           // [4096][768]
  bf16* xcW = xqB + (long)4096 * 768;            // [32768][768]
  bf16* xqW = xcW + (long)32768 * 768;           // [4096][768]
  bf16* xqV = xqW + (long)4096 * 768;            // [4096][768]
  bf16* xqVT = xqV + (long)4096 * 768;           // [16][768][256]
  bf16* G1 = xqVT + (long)16 * 768 * 256;        // [32768][768]

  (void)hipFuncSetAttribute(reinterpret_cast<const void*>(&gemm4b),
                            hipFuncAttributeMaxDynamicSharedMemorySize, 131072);
  (void)hipFuncSetAttribute(reinterpret_cast<const void*>(&attn4),
                            hipFuncAttributeMaxDynamicSharedMemorySize, 69632);

  // weight prep: Wct = [WC^T ; Vtop^T], Wqt = [WQ^T ; Vbot^T]
  transpose4<<<dim3(24, 24, 4), dim3(32, 8), 0, stream>>>(
      WC, WQ, V, V + (long)768 * 768,
      Wct, Wqt, Wct + (long)768 * 768, Wqt + (long)768 * 768);

  // input converts (grid-stride)
  convert_flat<<<3072, 256, 0, stream>>>(x_cont, xcB, (long)32768 * 768 / 4);
  convert_flat<<<768, 256, 0, stream>>>(x_ques, xqB, (long)4096 * 768 / 4);

  // xq fused projection: [xqW | xqV] = relu/id(xq @ [WQ | Vbot])
  gemm_bt_split<<<dim3(32, 12), 256, 0, stream>>>(xqB, 768, Wqt, 768, xqW, xqV, 768);
  transpose_bf16<<<dim3(24, 8, 16), dim3(32, 8), 0, stream>>>(
      xqV, xqVT, 256, 768, (long)256 * 768, (long)768 * 256);

  // xc fused projection: xcW (relu bf16) + G1 (bf16)
  gemm4b<<<768, 512, 131072, stream>>>(xcB, 768, Wct, 768, xcW, G1, 768);

  // attention + gate epilogue (no LDS staging in QK)
  attn4<<<512, 256, 69632, stream>>>(xcW, xqW, xqVT, G1, ques_len, out);
}